// Round 10
// baseline (2930.746 us; speedup 1.0000x reference)
//
#include <hip/hip_runtime.h>
#include <stdint.h>

// Problem constants (fixed seed, fixed shapes)
#define BB 16
#define TT 2048
#define NI 32
#define NN 2048
#define NO 32
#define WASH 64
#define TO (TT - WASH + 1)   // 1985
#define W 24                 // per-row ELL cap
#define WT 24                // per-thread combined (pair) slot cap — COMPILE-TIME
#define CH 16                // time-chunk for fused MFMA GEMMs
#define HBST 2048            // hb row stride in halfwords (row base == 0 mod 128 B: banks step-invariant)
#define HBROW 4096           // hb row stride in bytes
#define UROWB 4132           // u2 row stride in bytes (1033 dwords)
#define U2OFF 65536          // byte offset of u2 (= CH*HBROW)
#define C1OFF 131712         // copy1 base (U2OFF + CH*UROWB = 131648, padded to mod-128)
#define LDS_BYTES (C1OFF + 8192)   // 139904

typedef short bfvec __attribute__((ext_vector_type(8)));   // 8 bf16 in 4 VGPRs
typedef float f4_t  __attribute__((ext_vector_type(4)));

__device__ inline unsigned short f2bf(float f) {
  unsigned int u = __builtin_bit_cast(unsigned int, f);
  unsigned int r = u + 0x7fffu + ((u >> 16) & 1u);   // RNE
  return (unsigned short)(r >> 16);
}
__device__ inline float bf2f(unsigned short s) {
  unsigned int u = ((unsigned int)s) << 16;
  return __builtin_bit_cast(float, u);
}
__device__ inline float tanh_fast(float x) {
  x = fminf(15.f, fmaxf(-15.f, x));
  float e = __expf(x + x);
  float r = __builtin_amdgcn_rcpf(e + 1.0f);
  return (e - 1.0f) * r;
}

// ---------------- K1: dense A -> packed ELL (bf16 val << 16 | byte-offset col, NATURAL cols) ----
__global__ void build_ell(const float* __restrict__ A, uint32_t* __restrict__ ell,
                          uint32_t* __restrict__ deg) {
  int gw = (int)((blockIdx.x * blockDim.x + threadIdx.x) >> 6);  // one wave per row
  int lane = (int)(threadIdx.x & 63);
  if (gw >= NN) return;
  const float* row = A + (size_t)gw * NN;
  int base = 0;
  for (int c = 0; c < NN; c += 64) {
    float v = row[c + lane];
    bool nz = (v != 0.0f);
    unsigned long long mask = __ballot(nz);
    int pre = __popcll(mask & ((1ull << lane) - 1ull));
    if (nz) {
      int idx = base + pre;
      if (idx < W) {
        uint32_t packed = (((uint32_t)f2bf(v)) << 16) | (uint32_t)((c + lane) * 4);
        ell[(size_t)gw * W + idx] = packed;
      }
    }
    base += __popcll(mask);
  }
  int d = base < W ? base : W;
  if (lane == 0) deg[gw] = (uint32_t)d;
  for (int k = d + lane; k < W; k += 64) ell[(size_t)gw * W + k] = 0u;
}

// ---------------- K2: DETERMINISTIC rank sort by degree -> perm, invp (8 blocks parallel) ------
__global__ void sortperm(const uint32_t* __restrict__ deg, uint32_t* __restrict__ perm,
                         uint32_t* __restrict__ invp) {
  __shared__ int dg[NN];
  int tid = (int)threadIdx.x;                      // 256
  for (int i = tid; i < NN; i += 256) dg[i] = (int)deg[i];
  __syncthreads();
  int r = (int)blockIdx.x * 256 + tid;             // 8 blocks x 256 = 2048 rows
  int d = dg[r];
  int rank = 0;
  for (int j = 0; j < NN; ++j) {
    int dj = dg[j];
    rank += (dj < d) || (dj == d && j < r);
  }
  perm[rank] = (uint32_t)r;
  invp[r] = (uint32_t)rank;
}

// ---------------- K2c: rank sort of head-tail pairs by combined degree (4 blocks parallel) -----
__global__ void pairsort(const uint32_t* __restrict__ deg, const uint32_t* __restrict__ perm,
                         uint32_t* __restrict__ pairrank, uint32_t* __restrict__ pp) {
  __shared__ int ps[1024];
  int tid = (int)threadIdx.x;                      // 256
  for (int i = tid; i < 1024; i += 256) {
    int d0 = (int)deg[perm[i]]; if (d0 > W) d0 = W;
    int d1 = (int)deg[perm[2047 - i]]; if (d1 > W) d1 = W;
    int s = d0 + d1; if (s > WT) s = WT;
    ps[i] = s;
  }
  __syncthreads();
  int p = (int)blockIdx.x * 256 + tid;             // 4 blocks x 256 = 1024 pairs
  int s = ps[p];
  int rank = 0;
  for (int j = 0; j < 1024; ++j) {
    int sj = ps[j];
    rank += (sj < s) || (sj == s && j < p);
  }
  pairrank[p] = (uint32_t)rank;
  pp[rank] = (uint32_t)p;
}

// rank r -> store position (given pairrank)
__device__ inline int rank2pos(int r, const uint32_t* pairrank) {
  return (r < 1024) ? (2 * (int)pairrank[r]) : (2 * (int)pairrank[2047 - r] + 1);
}

// copy1 remap: owner thread t -> dword pos1 (bijective, breaks mod-32 congruence classes)
__device__ inline int c1pos(int t) {
  int l = t & 31, h = t >> 5;
  return (h << 5) | ((17 * l + 5 * h) & 31);
}

// ---------------- K2b: entry tables + HALF-AWARE 2-CHOICE CONFLICT SCHEDULER -------------------
// Even slots gather from copy0 (bank = owner&31), odd slots from copy1 (bank = (17l+5h)&31).
// Capacity 1 per (bank, 32-lane-half). 3 polite rounds + final round (urgent lanes force).
// Deterministic (rotated-priority ballots). wavecnt[blk] = exact slot count S in [8,24].
__global__ void build_pairs(const uint32_t* __restrict__ ell, const uint32_t* __restrict__ deg,
                            const uint32_t* __restrict__ perm, const uint32_t* __restrict__ invp,
                            const uint32_t* __restrict__ pairrank, const uint32_t* __restrict__ pp,
                            uint32_t* __restrict__ pa, uint32_t* __restrict__ pva,
                            uint32_t* __restrict__ pvb, uint32_t* __restrict__ wavecnt) {
  int blk = (int)blockIdx.x;     // 0..15 (rec-wave)
  int lane = (int)threadIdx.x;   // 0..63
  int half = lane >> 5;
  int t = blk * 64 + lane;
  int p = (int)pp[t];
  uint32_t a0_[WT], a1_[WT], u_[WT], w_[WT];
  int cnt = 0;
  {
    int ro = (int)perm[p];                       // y0 row
    int d = (int)deg[ro]; if (d > W) d = W;
    for (int k = 0; k < d && cnt < WT; ++k) {
      uint32_t e = ell[(size_t)ro * W + k];
      int pos = rank2pos((int)invp[(e & 0xffffu) >> 2], pairrank);
      a0_[cnt] = (uint32_t)(pos * 2);
      a1_[cnt] = (uint32_t)(c1pos(pos >> 1) * 4 + (pos & 1) * 2);
      u_[cnt] = e & 0xffff0000u;
      w_[cnt] = 0u;
      ++cnt;
    }
    ro = (int)perm[2047 - p];                    // y1 row
    d = (int)deg[ro]; if (d > W) d = W;
    for (int k = 0; k < d && cnt < WT; ++k) {
      uint32_t e = ell[(size_t)ro * W + k];
      int pos = rank2pos((int)invp[(e & 0xffffu) >> 2], pairrank);
      a0_[cnt] = (uint32_t)(pos * 2);
      a1_[cnt] = (uint32_t)(c1pos(pos >> 1) * 4 + (pos & 1) * 2);
      u_[cnt] = 0u;
      w_[cnt] = e & 0xffff0000u;
      ++cnt;
    }
  }
  // wave max -> exact variant size S (8..24)
  int m = cnt;
  #pragma unroll
  for (int off = 32; off; off >>= 1) m = max(m, __shfl_xor(m, off));
  int S = m < 8 ? 8 : (m > 24 ? 24 : m);
  if (lane == 0) wavecnt[blk] = (uint32_t)S;

  uint32_t sa[WT], su[WT], sw[WT];
  for (int s = 0; s < WT; ++s) {                 // defaults (slots >= S, never executed)
    sa[s] = ((uint32_t)((lane + s) & 31)) << 2;
    su[s] = 0u; sw[s] = 0u;
  }
  uint32_t used = 0;
  int rem = cnt;
  for (int s = 0; s < S; ++s) {
    int copy = s & 1;
    unsigned long long occ = 0ull;               // bit (half*32 + bank)
    bool placed = false;
    const int R = 4;
    for (int r = 0; r < R; ++r) {
      bool last = (r == R - 1);
      bool urgent = (rem >= S - s);
      int pk = -1, pb = 32;
      if (!placed && rem > 0) {
        for (int k = 0; k < WT; ++k) {           // first remaining entry with free bank (my half)
          if (k >= cnt) break;
          if ((used >> k) & 1u) continue;
          int b = copy ? (int)((a1_[k] >> 2) & 31u) : (int)((a0_[k] >> 2) & 31u);
          if (!((occ >> (half * 32 + b)) & 1ull)) { pk = k; pb = b; break; }
        }
        if (pk < 0 && last && urgent) {          // urgent: any remaining entry
          for (int k = 0; k < WT; ++k) {
            if (k >= cnt) break;
            if (!((used >> k) & 1u)) {
              pk = k;
              pb = copy ? (int)((a1_[k] >> 2) & 31u) : (int)((a0_[k] >> 2) & 31u);
              break;
            }
          }
        }
      }
      int shift = (s * 19 + r * 7) & 31;
      for (int b = 0; b < 32; ++b) {
        unsigned long long mb = __ballot(pb == b);
        if (!mb) continue;
        for (int h = 0; h < 2; ++h) {
          uint32_t mh = (uint32_t)(mb >> (h * 32));
          if (!mh) continue;
          bool freeb = !((occ >> (h * 32 + b)) & 1ull);
          uint32_t mhr = (mh >> shift) | (mh << ((32 - shift) & 31));
          int winpos = __ffs(mhr) - 1;
          int winlane = ((winpos + shift) & 31) + h * 32;
          if (freeb) occ |= 1ull << (h * 32 + b);
          if (pb == b && half == h && !placed) {
            bool win = (lane == winlane);
            if ((freeb && win) || (last && urgent)) {
              placed = true;
              used |= 1u << (unsigned)pk;
              sa[s] = copy ? a1_[pk] : a0_[pk];
              su[s] = u_[pk]; sw[s] = w_[pk];
              rem--;
            }
          }
        }
      }
    }
    if (!placed) {
      // pad: free bank in my half scanning from lane+s (reads valid h data, values are zero)
      int pick = (lane + s) & 31;
      for (int j = 0; j < 32; ++j) {
        int b = (lane + s + j) & 31;
        if (!((occ >> (half * 32 + b)) & 1ull)) { pick = b; break; }
      }
      sa[s] = ((uint32_t)pick) << 2;             // dword 'pick' has bank 'pick' in both copies
    }
  }
  for (int k = 0; k < WT; ++k) {
    pa[(size_t)t * WT + k] = sa[k];
    pva[(size_t)t * WT + k] = su[k];
    pvb[(size_t)t * WT + k] = sw[k];
  }
}

// ---------------- K3: Win/Wout -> MFMA fragment order (bf16 pairs), store-order n --------------
__global__ void build_frags(const float* __restrict__ Win, const float* __restrict__ Wout,
                            const uint32_t* __restrict__ perm, const uint32_t* __restrict__ pp,
                            uint32_t* __restrict__ winf, uint32_t* __restrict__ woutf) {
  int f = (int)(blockIdx.x * blockDim.x + threadIdx.x);  // 0..65535
  if (f < 32768) {
    int reg = f & 3, lane = (f >> 2) & 63, ntg = f >> 8;
    int n = (ntg << 4) + (lane & 15);
    int k = ((lane >> 4) << 3) + reg * 2;
    int p = (int)pp[n >> 1];
    int np = (int)perm[(n & 1) ? (2047 - p) : p];
    uint32_t lo = f2bf(Win[(size_t)np * NI + k]);
    uint32_t hi = f2bf(Win[(size_t)np * NI + k + 1]);
    winf[f] = lo | (hi << 16);
  } else {
    int g = f - 32768;
    int reg = g & 3, lane = (g >> 2) & 63, kt = (g >> 8) & 63, ot = g >> 14;
    int o = (ot << 4) + (lane & 15);
    int n = (kt << 5) + ((lane >> 4) << 3) + reg * 2;   // even
    int p = (int)pp[n >> 1];
    int n0 = (int)perm[p];
    int n1 = (int)perm[2047 - p];
    uint32_t lo = f2bf(Wout[(size_t)o * NN + n0]);
    uint32_t hi = f2bf(Wout[(size_t)o * NN + n1]);
    woutf[g] = lo | (hi << 16);
  }
}

// ---------------- K4: fused recurrence (1 workgroup per batch) ---------------------------------
// LDS: hb ring [16][4096B] at 0 | u2 [16][4132B] at U2OFF (oscratch overlay) | copy1 2x4096B at C1OFF
// Even slots read copy0 (po0 = prev ring row), odd slots read copy1 (po1 = prev parity row):
// compile-time base select per slot index — zero extra VALU.
#define ENT(K)                                                                       \
  {                                                                                  \
    float hv = bf2f(*(const unsigned short*)(smem + ((((K) & 1) ? po1 : po0)) + ea##K)); \
    y0 = __builtin_fmaf(__builtin_bit_cast(float, va##K), hv, y0);                   \
    y1 = __builtin_fmaf(__builtin_bit_cast(float, vb##K), hv, y1);                   \
  }

#define ENTS8  ENT(0) ENT(1) ENT(2) ENT(3) ENT(4) ENT(5) ENT(6) ENT(7)
#define ENTS9  ENTS8  ENT(8)
#define ENTS10 ENTS9  ENT(9)
#define ENTS11 ENTS10 ENT(10)
#define ENTS12 ENTS11 ENT(11)
#define ENTS13 ENTS12 ENT(12)
#define ENTS14 ENTS13 ENT(13)
#define ENTS15 ENTS14 ENT(14)
#define ENTS16 ENTS15 ENT(15)
#define ENTS17 ENTS16 ENT(16)
#define ENTS18 ENTS17 ENT(17)
#define ENTS19 ENTS18 ENT(18)
#define ENTS20 ENTS19 ENT(19)
#define ENTS21 ENTS20 ENT(20)
#define ENTS22 ENTS21 ENT(21)
#define ENTS23 ENTS22 ENT(22)
#define ENTS24 ENTS23 ENT(23)

// rolled 16-step loop (forced no-unroll: 17 variants must fit I$)
#define STEPLOOP(ENTS)                                                               \
  _Pragma("unroll 1")                                                                \
  for (int tt = 0; tt < CH; ++tt) {                                                  \
    const int po0 = ((tt + CH - 1) & (CH - 1)) << 12;                                \
    const int po1 = C1OFF + (((tt + 1) & 1) << 12);                                  \
    uint32_t uw = *(const uint32_t*)(smem + u2a + tt * UROWB);                       \
    float y0 = bf2f((unsigned short)(uw & 0xffffu));                                 \
    float y1 = bf2f((unsigned short)(uw >> 16));                                     \
    ENTS                                                                             \
    float hn0 = 0.1f * h0 + 0.9f * tanh_fast(y0);                                    \
    float hn1 = 0.1f * h1 + 0.9f * tanh_fast(y1);                                    \
    uint32_t wpk = (uint32_t)f2bf(hn0) | ((uint32_t)f2bf(hn1) << 16);                \
    *(uint32_t*)(smem + hwa + (tt << 12)) = wpk;                                     \
    *(uint32_t*)(smem + c1wa + ((tt & 1) << 12)) = wpk;                              \
    h0 = hn0; h1 = hn1;                                                              \
    __syncthreads();                                                                 \
  }

__global__ __launch_bounds__(1024, 1) void rec_kernel(
    const float* __restrict__ x,
    const uint32_t* __restrict__ pa, const uint32_t* __restrict__ pva,
    const uint32_t* __restrict__ pvb, const uint32_t* __restrict__ wavecnt,
    const uint32_t* __restrict__ winf, const uint32_t* __restrict__ woutf,
    float* __restrict__ out) {
  extern __shared__ char smem[];
  unsigned short* hb = (unsigned short*)smem;
  float* oscratch = (float*)(smem + U2OFF);

  const int tid = (int)threadIdx.x;
  const int b = (int)blockIdx.x;
  const int lane = tid & 63;
  const int wv = tid >> 6;
  const int la15 = lane & 15;
  const int lg = lane >> 4;
  const int u2a = U2OFF + (tid << 2);
  const int hwa = tid << 2;
  const int c1wa = C1OFF + (((tid >> 5 << 5) | ((17 * (tid & 31) + 5 * (tid >> 5)) & 31)) << 2);

  int cnt = __builtin_amdgcn_readfirstlane((int)wavecnt[wv]);

  // entry tables -> 72 NAMED scalars (no arrays, no alloca, no scratch)
  uint32_t ea0, ea1, ea2, ea3, ea4, ea5, ea6, ea7, ea8, ea9, ea10, ea11,
           ea12, ea13, ea14, ea15, ea16, ea17, ea18, ea19, ea20, ea21, ea22, ea23;
  uint32_t va0, va1, va2, va3, va4, va5, va6, va7, va8, va9, va10, va11,
           va12, va13, va14, va15, va16, va17, va18, va19, va20, va21, va22, va23;
  uint32_t vb0, vb1, vb2, vb3, vb4, vb5, vb6, vb7, vb8, vb9, vb10, vb11,
           vb12, vb13, vb14, vb15, vb16, vb17, vb18, vb19, vb20, vb21, vb22, vb23;
  {
    const uint4* qa = (const uint4*)(pa + (size_t)tid * WT);
    const uint4* qv = (const uint4*)(pva + (size_t)tid * WT);
    const uint4* qw = (const uint4*)(pvb + (size_t)tid * WT);
    uint4 A0 = qa[0], A1 = qa[1], A2 = qa[2], A3 = qa[3], A4 = qa[4], A5 = qa[5];
    uint4 V0 = qv[0], V1 = qv[1], V2 = qv[2], V3 = qv[3], V4 = qv[4], V5 = qv[5];
    uint4 B0 = qw[0], B1 = qw[1], B2 = qw[2], B3 = qw[3], B4 = qw[4], B5 = qw[5];
    ea0 = A0.x; ea1 = A0.y; ea2 = A0.z; ea3 = A0.w;
    ea4 = A1.x; ea5 = A1.y; ea6 = A1.z; ea7 = A1.w;
    ea8 = A2.x; ea9 = A2.y; ea10 = A2.z; ea11 = A2.w;
    ea12 = A3.x; ea13 = A3.y; ea14 = A3.z; ea15 = A3.w;
    ea16 = A4.x; ea17 = A4.y; ea18 = A4.z; ea19 = A4.w;
    ea20 = A5.x; ea21 = A5.y; ea22 = A5.z; ea23 = A5.w;
    va0 = V0.x; va1 = V0.y; va2 = V0.z; va3 = V0.w;
    va4 = V1.x; va5 = V1.y; va6 = V1.z; va7 = V1.w;
    va8 = V2.x; va9 = V2.y; va10 = V2.z; va11 = V2.w;
    va12 = V3.x; va13 = V3.y; va14 = V3.z; va15 = V3.w;
    va16 = V4.x; va17 = V4.y; va18 = V4.z; va19 = V4.w;
    va20 = V5.x; va21 = V5.y; va22 = V5.z; va23 = V5.w;
    vb0 = B0.x; vb1 = B0.y; vb2 = B0.z; vb3 = B0.w;
    vb4 = B1.x; vb5 = B1.y; vb6 = B1.z; vb7 = B1.w;
    vb8 = B2.x; vb9 = B2.y; vb10 = B2.z; vb11 = B2.w;
    vb12 = B3.x; vb13 = B3.y; vb14 = B3.z; vb15 = B3.w;
    vb16 = B4.x; vb17 = B4.y; vb18 = B4.z; vb19 = B4.w;
    vb20 = B5.x; vb21 = B5.y; vb22 = B5.z; vb23 = B5.w;
  }

  // h(t=-1) = 0: zero hb ring row 15 and copy1 parity-1 row
  *(uint32_t*)(smem + 15 * HBROW + (tid << 2)) = 0u;
  *(uint32_t*)(smem + C1OFF + 4096 + (tid << 2)) = 0u;
  float h0 = 0.0f, h1 = 0.0f;

  for (int c = 0; c < TT / CH; ++c) {
    const int t0 = c * CH;

    // ---- phase A: u2 = Win_store . x_chunk^T via MFMA (D row=n, col=t); wave wv: n in [wv*128,+128)
    {
      const float* xp = x + ((size_t)b * TT + (t0 + la15)) * NI + (lg << 3);
      float4 x0 = *(const float4*)xp;
      float4 x1 = *(const float4*)(xp + 4);
      union { unsigned short u16[8]; bfvec v; } af;   // B-operand: col=t=la15, k=i
      af.u16[0]=f2bf(x0.x); af.u16[1]=f2bf(x0.y); af.u16[2]=f2bf(x0.z); af.u16[3]=f2bf(x0.w);
      af.u16[4]=f2bf(x1.x); af.u16[5]=f2bf(x1.y); af.u16[6]=f2bf(x1.z); af.u16[7]=f2bf(x1.w);
      #pragma unroll
      for (int nt = 0; nt < 8; ++nt) {
        int ntg = (wv << 3) + nt;
        union { uint4 q; bfvec v; } bw;               // A-operand: row=n=la15-in-tile, k=i
        bw.q = *(const uint4*)(winf + (((size_t)ntg * 64 + lane) << 2));
        f4_t acc = {0.f, 0.f, 0.f, 0.f};
        acc = __builtin_amdgcn_mfma_f32_16x16x32_bf16(bw.v, af.v, acc, 0, 0, 0);
        int dw = (ntg << 3) + (lg << 1);              // dword index = n>>1
        uint32_t w0 = (uint32_t)f2bf(acc[0]) | ((uint32_t)f2bf(acc[1]) << 16);
        uint32_t w1 = (uint32_t)f2bf(acc[2]) | ((uint32_t)f2bf(acc[3]) << 16);
        char* ub = smem + U2OFF + la15 * UROWB + (dw << 2);
        *(uint32_t*)(ub) = w0;
        *(uint32_t*)(ub + 4) = w1;
      }
    }
    __syncthreads();

    // ---- phase B: 16 recurrence steps; wave-uniform variant on exact scheduled slot count
    asm volatile("" : "+s"(cnt));   // launder: block loop-unswitching (17x I$ blowup)
    if      (cnt <= 8)  { STEPLOOP(ENTS8)  }
    else if (cnt == 9)  { STEPLOOP(ENTS9)  }
    else if (cnt == 10) { STEPLOOP(ENTS10) }
    else if (cnt == 11) { STEPLOOP(ENTS11) }
    else if (cnt == 12) { STEPLOOP(ENTS12) }
    else if (cnt == 13) { STEPLOOP(ENTS13) }
    else if (cnt == 14) { STEPLOOP(ENTS14) }
    else if (cnt == 15) { STEPLOOP(ENTS15) }
    else if (cnt == 16) { STEPLOOP(ENTS16) }
    else if (cnt == 17) { STEPLOOP(ENTS17) }
    else if (cnt == 18) { STEPLOOP(ENTS18) }
    else if (cnt == 19) { STEPLOOP(ENTS19) }
    else if (cnt == 20) { STEPLOOP(ENTS20) }
    else if (cnt == 21) { STEPLOOP(ENTS21) }
    else if (cnt == 22) { STEPLOOP(ENTS22) }
    else if (cnt == 23) { STEPLOOP(ENTS23) }
    else                { STEPLOOP(ENTS24) }

    // ---- phase C: out_chunk = hb @ Wout^T via MFMA; wave wv covers K in [wv*128, +128)
    {
      f4_t oa0 = {0.f,0.f,0.f,0.f}, oa1 = {0.f,0.f,0.f,0.f};
      #pragma unroll
      for (int k4 = 0; k4 < 4; ++k4) {
        int kt = (wv << 2) + k4;
        union { uint4 q; bfvec v; } ha, w0, w1;
        ha.q = *(const uint4*)(hb + (size_t)la15 * HBST + (kt << 5) + (lg << 3));
        w0.q = *(const uint4*)(woutf + (((size_t)(kt) * 64 + lane) << 2));
        w1.q = *(const uint4*)(woutf + (((size_t)(64 + kt) * 64 + lane) << 2));
        oa0 = __builtin_amdgcn_mfma_f32_16x16x32_bf16(ha.v, w0.v, oa0, 0, 0, 0);
        oa1 = __builtin_amdgcn_mfma_f32_16x16x32_bf16(ha.v, w1.v, oa1, 0, 0, 0);
      }
      float* os = oscratch + (wv << 9);
      int tb = lg << 2;
      #pragma unroll
      for (int r = 0; r < 4; ++r) os[(tb + r) * 32 + la15] = oa0[r];
      #pragma unroll
      for (int r = 0; r < 4; ++r) os[(tb + r) * 32 + 16 + la15] = oa1[r];
    }
    __syncthreads();
    if (tid < 512) {
      float s = 0.0f;
      #pragma unroll
      for (int w2 = 0; w2 < 16; ++w2) s += oscratch[(w2 << 9) + tid];
      int tg = t0 + (tid >> 5);
      if (tg >= WASH - 1)
        out[((size_t)b * TO + (tg - (WASH - 1))) * NO + (tid & 31)] = s;
    }
    __syncthreads();  // protect u2/oscratch before next chunk's phase A
  }
}

extern "C" void kernel_launch(void* const* d_in, const int* in_sizes, int n_in,
                              void* d_out, int out_size, void* d_ws, size_t ws_size,
                              hipStream_t stream) {
  (void)in_sizes; (void)n_in; (void)out_size; (void)ws_size;
  const float* x    = (const float*)d_in[0];
  const float* Win  = (const float*)d_in[1];
  const float* A    = (const float*)d_in[2];
  const float* Wout = (const float*)d_in[3];
  float* out = (float*)d_out;

  char* ws = (char*)d_ws;
  uint32_t* ell      = (uint32_t*)(ws);              // 196608
  uint32_t* deg      = (uint32_t*)(ws + 196608);     // 8192
  uint32_t* perm     = (uint32_t*)(ws + 204800);     // 8192
  uint32_t* invp     = (uint32_t*)(ws + 212992);     // 8192
  uint32_t* pairrank = (uint32_t*)(ws + 221184);     // 4096
  uint32_t* pp       = (uint32_t*)(ws + 225280);     // 4096
  uint32_t* wavecnt  = (uint32_t*)(ws + 229376);     // 128
  uint32_t* pa       = (uint32_t*)(ws + 229504);     // 98304
  uint32_t* pva      = (uint32_t*)(ws + 327808);     // 98304
  uint32_t* pvb      = (uint32_t*)(ws + 426112);     // 98304
  uint32_t* winf     = (uint32_t*)(ws + 524416);     // 131072
  uint32_t* woutf    = (uint32_t*)(ws + 655488);     // 131072 (total 786560 B)

  hipFuncSetAttribute((const void*)rec_kernel,
                      hipFuncAttributeMaxDynamicSharedMemorySize, 160 * 1024);

  hipLaunchKernelGGL(build_ell, dim3(512), dim3(256), 0, stream, A, ell, deg);
  hipLaunchKernelGGL(sortperm, dim3(8), dim3(256), 0, stream, deg, perm, invp);
  hipLaunchKernelGGL(pairsort, dim3(4), dim3(256), 0, stream, deg, perm, pairrank, pp);
  hipLaunchKernelGGL(build_pairs, dim3(16), dim3(64), 0, stream,
                     ell, deg, perm, invp, pairrank, pp, pa, pva, pvb, wavecnt);
  hipLaunchKernelGGL(build_frags, dim3(256), dim3(256), 0, stream, Win, Wout, perm, pp, winf, woutf);
  hipLaunchKernelGGL(rec_kernel, dim3(16), dim3(1024), LDS_BYTES, stream,
                     x, pa, pva, pvb, wavecnt, winf, woutf, out);
}

// Round 11
// 2915.269 us; speedup vs baseline: 1.0053x; 1.0053x over previous
//
#include <hip/hip_runtime.h>
#include <stdint.h>

// Problem constants (fixed seed, fixed shapes)
#define BB 16
#define TT 2048
#define NI 32
#define NN 2048
#define NO 32
#define WASH 64
#define TO (TT - WASH + 1)   // 1985
#define W 24                 // per-row ELL cap
#define WT 24                // per-thread combined (pair) slot cap — COMPILE-TIME
#define CH 16                // time-chunk for fused MFMA GEMMs
// LDS layout (bytes):
//   hb   [2][4096]      @ 0       : parity ring for gathers (row base ≡0 mod 128 -> banks step-invariant)
//   u2   [16][4132]     @ 8192    : input projection (stride 1033 dwords); oscratch overlays in phase C
//   hbT  [16][4148]     @ 74368   : per-step h history, stride 1037 dwords (≡13 mod 32 -> phase C clean)
#define U2OFF 8192
#define UROWB 4132
#define HBT_OFF 74368
#define HBTROW 4148
#define OSW 35               // oscratch row stride (dwords), ≡3 mod 32 -> same-half-clean
#define OSWAVE 560           // per-wave oscratch dwords (16*35)
#define LDS_BYTES (HBT_OFF + CH*HBTROW)   // 74368 + 66368 = 140736

typedef short bfvec __attribute__((ext_vector_type(8)));   // 8 bf16 in 4 VGPRs
typedef float f4_t  __attribute__((ext_vector_type(4)));

__device__ inline unsigned short f2bf(float f) {
  unsigned int u = __builtin_bit_cast(unsigned int, f);
  unsigned int r = u + 0x7fffu + ((u >> 16) & 1u);   // RNE
  return (unsigned short)(r >> 16);
}
__device__ inline float bf2f(unsigned short s) {
  unsigned int u = ((unsigned int)s) << 16;
  return __builtin_bit_cast(float, u);
}
__device__ inline float tanh_fast(float x) {
  x = fminf(15.f, fmaxf(-15.f, x));
  float e = __expf(x + x);
  float r = __builtin_amdgcn_rcpf(e + 1.0f);
  return (e - 1.0f) * r;
}

// ---------------- K1: dense A -> packed ELL (bf16 val << 16 | byte-offset col, NATURAL cols) ----
__global__ void build_ell(const float* __restrict__ A, uint32_t* __restrict__ ell,
                          uint32_t* __restrict__ deg) {
  int gw = (int)((blockIdx.x * blockDim.x + threadIdx.x) >> 6);  // one wave per row
  int lane = (int)(threadIdx.x & 63);
  if (gw >= NN) return;
  const float* row = A + (size_t)gw * NN;
  int base = 0;
  for (int c = 0; c < NN; c += 64) {
    float v = row[c + lane];
    bool nz = (v != 0.0f);
    unsigned long long mask = __ballot(nz);
    int pre = __popcll(mask & ((1ull << lane) - 1ull));
    if (nz) {
      int idx = base + pre;
      if (idx < W) {
        uint32_t packed = (((uint32_t)f2bf(v)) << 16) | (uint32_t)((c + lane) * 4);
        ell[(size_t)gw * W + idx] = packed;
      }
    }
    base += __popcll(mask);
  }
  int d = base < W ? base : W;
  if (lane == 0) deg[gw] = (uint32_t)d;
  for (int k = d + lane; k < W; k += 64) ell[(size_t)gw * W + k] = 0u;
}

// ---------------- K2: DETERMINISTIC rank sort by degree -> perm, invp (8 blocks parallel) ------
__global__ void sortperm(const uint32_t* __restrict__ deg, uint32_t* __restrict__ perm,
                         uint32_t* __restrict__ invp) {
  __shared__ int dg[NN];
  int tid = (int)threadIdx.x;                      // 256
  for (int i = tid; i < NN; i += 256) dg[i] = (int)deg[i];
  __syncthreads();
  int r = (int)blockIdx.x * 256 + tid;             // 8 blocks x 256 = 2048 rows
  int d = dg[r];
  int rank = 0;
  for (int j = 0; j < NN; ++j) {
    int dj = dg[j];
    rank += (dj < d) || (dj == d && j < r);
  }
  perm[rank] = (uint32_t)r;
  invp[r] = (uint32_t)rank;
}

// ---------------- K2c: rank sort of head-tail pairs by combined degree (4 blocks parallel) -----
__global__ void pairsort(const uint32_t* __restrict__ deg, const uint32_t* __restrict__ perm,
                         uint32_t* __restrict__ pairrank, uint32_t* __restrict__ pp) {
  __shared__ int ps[1024];
  int tid = (int)threadIdx.x;                      // 256
  for (int i = tid; i < 1024; i += 256) {
    int d0 = (int)deg[perm[i]]; if (d0 > W) d0 = W;
    int d1 = (int)deg[perm[2047 - i]]; if (d1 > W) d1 = W;
    int s = d0 + d1; if (s > WT) s = WT;
    ps[i] = s;
  }
  __syncthreads();
  int p = (int)blockIdx.x * 256 + tid;             // 4 blocks x 256 = 1024 pairs
  int s = ps[p];
  int rank = 0;
  for (int j = 0; j < 1024; ++j) {
    int sj = ps[j];
    rank += (sj < s) || (sj == s && j < p);
  }
  pairrank[p] = (uint32_t)rank;
  pp[rank] = (uint32_t)p;
}

// rank r -> store position (given pairrank)
__device__ inline int rank2pos(int r, const uint32_t* pairrank) {
  return (r < 1024) ? (2 * (int)pairrank[r]) : (2 * (int)pairrank[2047 - r] + 1);
}

// ---------------- K2b: entry tables + HALF-AWARE CONFLICT SCHEDULER (single copy) --------------
// Gather bank = (pos>>1)&31 = owner-thread&31, identical both parity rows (4096-B stride).
// Capacity 1 per (bank, 32-lane-half). 3 polite rounds + final (urgent lanes force).
// Deterministic (rotated-priority ballots). wavecnt[blk] = exact slot count S in [8,24].
__global__ void build_pairs(const uint32_t* __restrict__ ell, const uint32_t* __restrict__ deg,
                            const uint32_t* __restrict__ perm, const uint32_t* __restrict__ invp,
                            const uint32_t* __restrict__ pairrank, const uint32_t* __restrict__ pp,
                            uint32_t* __restrict__ pa, uint32_t* __restrict__ pva,
                            uint32_t* __restrict__ pvb, uint32_t* __restrict__ wavecnt) {
  int blk = (int)blockIdx.x;     // 0..15 (rec-wave)
  int lane = (int)threadIdx.x;   // 0..63
  int half = lane >> 5;
  int t = blk * 64 + lane;
  int p = (int)pp[t];
  uint32_t a_[WT], u_[WT], w_[WT];
  int cnt = 0;
  {
    int ro = (int)perm[p];                       // y0 row
    int d = (int)deg[ro]; if (d > W) d = W;
    for (int k = 0; k < d && cnt < WT; ++k) {
      uint32_t e = ell[(size_t)ro * W + k];
      int pos = rank2pos((int)invp[(e & 0xffffu) >> 2], pairrank);
      a_[cnt] = (uint32_t)(pos * 2);
      u_[cnt] = e & 0xffff0000u;
      w_[cnt] = 0u;
      ++cnt;
    }
    ro = (int)perm[2047 - p];                    // y1 row
    d = (int)deg[ro]; if (d > W) d = W;
    for (int k = 0; k < d && cnt < WT; ++k) {
      uint32_t e = ell[(size_t)ro * W + k];
      int pos = rank2pos((int)invp[(e & 0xffffu) >> 2], pairrank);
      a_[cnt] = (uint32_t)(pos * 2);
      u_[cnt] = 0u;
      w_[cnt] = e & 0xffff0000u;
      ++cnt;
    }
  }
  // wave max -> exact variant size S (8..24)
  int m = cnt;
  #pragma unroll
  for (int off = 32; off; off >>= 1) m = max(m, __shfl_xor(m, off));
  int S = m < 8 ? 8 : (m > 24 ? 24 : m);
  if (lane == 0) wavecnt[blk] = (uint32_t)S;

  uint32_t sa[WT], su[WT], sw[WT];
  for (int s = 0; s < WT; ++s) {                 // defaults (pads / slots >= S)
    sa[s] = ((uint32_t)((lane + s) & 31)) << 2;
    su[s] = 0u; sw[s] = 0u;
  }
  uint32_t used = 0;
  int rem = cnt;
  for (int s = 0; s < S; ++s) {
    unsigned long long occ = 0ull;               // bit (half*32 + bank)
    bool placed = false;
    const int R = 4;
    for (int r = 0; r < R; ++r) {
      bool last = (r == R - 1);
      bool urgent = (rem >= S - s);
      int pk = -1, pb = 32;
      if (!placed && rem > 0) {
        for (int k = 0; k < WT; ++k) {           // first remaining entry with free bank (my half)
          if (k >= cnt) break;
          if ((used >> k) & 1u) continue;
          int b = (int)((a_[k] >> 2) & 31u);
          if (!((occ >> (half * 32 + b)) & 1ull)) { pk = k; pb = b; break; }
        }
        if (pk < 0 && last && urgent) {          // urgent: any remaining entry
          for (int k = 0; k < WT; ++k) {
            if (k >= cnt) break;
            if (!((used >> k) & 1u)) {
              pk = k;
              pb = (int)((a_[k] >> 2) & 31u);
              break;
            }
          }
        }
      }
      int shift = (s * 19 + r * 7) & 31;
      for (int b = 0; b < 32; ++b) {
        unsigned long long mb = __ballot(pb == b);
        if (!mb) continue;
        for (int h = 0; h < 2; ++h) {
          uint32_t mh = (uint32_t)(mb >> (h * 32));
          if (!mh) continue;
          bool freeb = !((occ >> (h * 32 + b)) & 1ull);
          uint32_t mhr = (mh >> shift) | (mh << ((32 - shift) & 31));
          int winpos = __ffs(mhr) - 1;
          int winlane = ((winpos + shift) & 31) + h * 32;
          if (freeb) occ |= 1ull << (h * 32 + b);
          if (pb == b && half == h && !placed) {
            bool win = (lane == winlane);
            if ((freeb && win) || (last && urgent)) {
              placed = true;
              used |= 1u << (unsigned)pk;
              sa[s] = a_[pk];
              su[s] = u_[pk]; sw[s] = w_[pk];
              rem--;
            }
          }
        }
      }
    }
    if (!placed) {
      // pad: free bank in my half scanning from lane+s (reads valid h data, values are zero)
      int pick = (lane + s) & 31;
      for (int j = 0; j < 32; ++j) {
        int b = (lane + s + j) & 31;
        if (!((occ >> (half * 32 + b)) & 1ull)) { pick = b; break; }
      }
      sa[s] = ((uint32_t)pick) << 2;
    }
  }
  for (int k = 0; k < WT; ++k) {
    pa[(size_t)t * WT + k] = sa[k];
    pva[(size_t)t * WT + k] = su[k];
    pvb[(size_t)t * WT + k] = sw[k];
  }
}

// ---------------- K3: Win/Wout -> MFMA fragment order (bf16 pairs), store-order n --------------
__global__ void build_frags(const float* __restrict__ Win, const float* __restrict__ Wout,
                            const uint32_t* __restrict__ perm, const uint32_t* __restrict__ pp,
                            uint32_t* __restrict__ winf, uint32_t* __restrict__ woutf) {
  int f = (int)(blockIdx.x * blockDim.x + threadIdx.x);  // 0..65535
  if (f < 32768) {
    int reg = f & 3, lane = (f >> 2) & 63, ntg = f >> 8;
    int n = (ntg << 4) + (lane & 15);
    int k = ((lane >> 4) << 3) + reg * 2;
    int p = (int)pp[n >> 1];
    int np = (int)perm[(n & 1) ? (2047 - p) : p];
    uint32_t lo = f2bf(Win[(size_t)np * NI + k]);
    uint32_t hi = f2bf(Win[(size_t)np * NI + k + 1]);
    winf[f] = lo | (hi << 16);
  } else {
    int g = f - 32768;
    int reg = g & 3, lane = (g >> 2) & 63, kt = (g >> 8) & 63, ot = g >> 14;
    int o = (ot << 4) + (lane & 15);
    int n = (kt << 5) + ((lane >> 4) << 3) + reg * 2;   // even
    int p = (int)pp[n >> 1];
    int n0 = (int)perm[p];
    int n1 = (int)perm[2047 - p];
    uint32_t lo = f2bf(Wout[(size_t)o * NN + n0]);
    uint32_t hi = f2bf(Wout[(size_t)o * NN + n1]);
    woutf[g] = lo | (hi << 16);
  }
}

// ---------------- K4: fused recurrence (1 workgroup per batch) ---------------------------------
// Gathers read hb parity row (4096-B stride, step-invariant banks). Each step writes the packed
// h-pair b32 twice: hb (gather ring) and hbT (stride-1037-dword history for conflict-free phase C).
#define ENT(K)                                                                       \
  {                                                                                  \
    float hv = bf2f(*(const unsigned short*)(smem + po0 + ea##K));                   \
    y0 = __builtin_fmaf(__builtin_bit_cast(float, va##K), hv, y0);                   \
    y1 = __builtin_fmaf(__builtin_bit_cast(float, vb##K), hv, y1);                   \
  }

#define ENTS8  ENT(0) ENT(1) ENT(2) ENT(3) ENT(4) ENT(5) ENT(6) ENT(7)
#define ENTS9  ENTS8  ENT(8)
#define ENTS10 ENTS9  ENT(9)
#define ENTS11 ENTS10 ENT(10)
#define ENTS12 ENTS11 ENT(11)
#define ENTS13 ENTS12 ENT(12)
#define ENTS14 ENTS13 ENT(13)
#define ENTS15 ENTS14 ENT(14)
#define ENTS16 ENTS15 ENT(15)
#define ENTS17 ENTS16 ENT(16)
#define ENTS18 ENTS17 ENT(17)
#define ENTS19 ENTS18 ENT(18)
#define ENTS20 ENTS19 ENT(19)
#define ENTS21 ENTS20 ENT(20)
#define ENTS22 ENTS21 ENT(21)
#define ENTS23 ENTS22 ENT(22)
#define ENTS24 ENTS23 ENT(23)

// rolled 16-step loop (forced no-unroll: 17 variants must fit I$)
#define STEPLOOP(ENTS)                                                               \
  _Pragma("unroll 1")                                                                \
  for (int tt = 0; tt < CH; ++tt) {                                                  \
    const int po0 = ((tt + 1) & 1) << 12;                                            \
    uint32_t uw = *(const uint32_t*)(smem + u2a + tt * UROWB);                       \
    float y0 = bf2f((unsigned short)(uw & 0xffffu));                                 \
    float y1 = bf2f((unsigned short)(uw >> 16));                                     \
    ENTS                                                                             \
    float hn0 = 0.1f * h0 + 0.9f * tanh_fast(y0);                                    \
    float hn1 = 0.1f * h1 + 0.9f * tanh_fast(y1);                                    \
    uint32_t wpk = (uint32_t)f2bf(hn0) | ((uint32_t)f2bf(hn1) << 16);                \
    *(uint32_t*)(smem + hwa + ((tt & 1) << 12)) = wpk;                               \
    *(uint32_t*)(smem + hbtwa + tt * HBTROW) = wpk;                                  \
    h0 = hn0; h1 = hn1;                                                              \
    __syncthreads();                                                                 \
  }

__global__ __launch_bounds__(1024, 1) void rec_kernel(
    const float* __restrict__ x,
    const uint32_t* __restrict__ pa, const uint32_t* __restrict__ pva,
    const uint32_t* __restrict__ pvb, const uint32_t* __restrict__ wavecnt,
    const uint32_t* __restrict__ winf, const uint32_t* __restrict__ woutf,
    float* __restrict__ out) {
  extern __shared__ char smem[];
  float* oscratch = (float*)(smem + U2OFF);       // overlays u2 during phase C

  const int tid = (int)threadIdx.x;
  const int b = (int)blockIdx.x;
  const int lane = tid & 63;
  const int wv = tid >> 6;
  const int la15 = lane & 15;
  const int lg = lane >> 4;
  const int u2a = U2OFF + (tid << 2);
  const int hwa = tid << 2;
  const int hbtwa = HBT_OFF + (tid << 2);

  int cnt = __builtin_amdgcn_readfirstlane((int)wavecnt[wv]);

  // entry tables -> 72 NAMED scalars (no arrays, no alloca, no scratch)
  uint32_t ea0, ea1, ea2, ea3, ea4, ea5, ea6, ea7, ea8, ea9, ea10, ea11,
           ea12, ea13, ea14, ea15, ea16, ea17, ea18, ea19, ea20, ea21, ea22, ea23;
  uint32_t va0, va1, va2, va3, va4, va5, va6, va7, va8, va9, va10, va11,
           va12, va13, va14, va15, va16, va17, va18, va19, va20, va21, va22, va23;
  uint32_t vb0, vb1, vb2, vb3, vb4, vb5, vb6, vb7, vb8, vb9, vb10, vb11,
           vb12, vb13, vb14, vb15, vb16, vb17, vb18, vb19, vb20, vb21, vb22, vb23;
  {
    const uint4* qa = (const uint4*)(pa + (size_t)tid * WT);
    const uint4* qv = (const uint4*)(pva + (size_t)tid * WT);
    const uint4* qw = (const uint4*)(pvb + (size_t)tid * WT);
    uint4 A0 = qa[0], A1 = qa[1], A2 = qa[2], A3 = qa[3], A4 = qa[4], A5 = qa[5];
    uint4 V0 = qv[0], V1 = qv[1], V2 = qv[2], V3 = qv[3], V4 = qv[4], V5 = qv[5];
    uint4 B0 = qw[0], B1 = qw[1], B2 = qw[2], B3 = qw[3], B4 = qw[4], B5 = qw[5];
    ea0 = A0.x; ea1 = A0.y; ea2 = A0.z; ea3 = A0.w;
    ea4 = A1.x; ea5 = A1.y; ea6 = A1.z; ea7 = A1.w;
    ea8 = A2.x; ea9 = A2.y; ea10 = A2.z; ea11 = A2.w;
    ea12 = A3.x; ea13 = A3.y; ea14 = A3.z; ea15 = A3.w;
    ea16 = A4.x; ea17 = A4.y; ea18 = A4.z; ea19 = A4.w;
    ea20 = A5.x; ea21 = A5.y; ea22 = A5.z; ea23 = A5.w;
    va0 = V0.x; va1 = V0.y; va2 = V0.z; va3 = V0.w;
    va4 = V1.x; va5 = V1.y; va6 = V1.z; va7 = V1.w;
    va8 = V2.x; va9 = V2.y; va10 = V2.z; va11 = V2.w;
    va12 = V3.x; va13 = V3.y; va14 = V3.z; va15 = V3.w;
    va16 = V4.x; va17 = V4.y; va18 = V4.z; va19 = V4.w;
    va20 = V5.x; va21 = V5.y; va22 = V5.z; va23 = V5.w;
    vb0 = B0.x; vb1 = B0.y; vb2 = B0.z; vb3 = B0.w;
    vb4 = B1.x; vb5 = B1.y; vb6 = B1.z; vb7 = B1.w;
    vb8 = B2.x; vb9 = B2.y; vb10 = B2.z; vb11 = B2.w;
    vb12 = B3.x; vb13 = B3.y; vb14 = B3.z; vb15 = B3.w;
    vb16 = B4.x; vb17 = B4.y; vb18 = B4.z; vb19 = B4.w;
    vb20 = B5.x; vb21 = B5.y; vb22 = B5.z; vb23 = B5.w;
  }

  // h(t=-1) = 0: zero hb parity row 1 (step 0 reads po0 = 4096)
  *(uint32_t*)(smem + 4096 + (tid << 2)) = 0u;
  float h0 = 0.0f, h1 = 0.0f;

  for (int c = 0; c < TT / CH; ++c) {
    const int t0 = c * CH;

    // ---- phase A: u2 = Win_store . x_chunk^T via MFMA (D row=n, col=t); wave wv: n in [wv*128,+128)
    {
      const float* xp = x + ((size_t)b * TT + (t0 + la15)) * NI + (lg << 3);
      float4 x0 = *(const float4*)xp;
      float4 x1 = *(const float4*)(xp + 4);
      union { unsigned short u16[8]; bfvec v; } af;   // B-operand: col=t=la15, k=i
      af.u16[0]=f2bf(x0.x); af.u16[1]=f2bf(x0.y); af.u16[2]=f2bf(x0.z); af.u16[3]=f2bf(x0.w);
      af.u16[4]=f2bf(x1.x); af.u16[5]=f2bf(x1.y); af.u16[6]=f2bf(x1.z); af.u16[7]=f2bf(x1.w);
      #pragma unroll
      for (int nt = 0; nt < 8; ++nt) {
        int ntg = (wv << 3) + nt;
        union { uint4 q; bfvec v; } bw;               // A-operand: row=n=la15-in-tile, k=i
        bw.q = *(const uint4*)(winf + (((size_t)ntg * 64 + lane) << 2));
        f4_t acc = {0.f, 0.f, 0.f, 0.f};
        acc = __builtin_amdgcn_mfma_f32_16x16x32_bf16(bw.v, af.v, acc, 0, 0, 0);
        int dw = (ntg << 3) + (lg << 1);              // dword index = n>>1
        uint32_t w0 = (uint32_t)f2bf(acc[0]) | ((uint32_t)f2bf(acc[1]) << 16);
        uint32_t w1 = (uint32_t)f2bf(acc[2]) | ((uint32_t)f2bf(acc[3]) << 16);
        char* ub = smem + U2OFF + la15 * UROWB + (dw << 2);
        *(uint32_t*)(ub) = w0;
        *(uint32_t*)(ub + 4) = w1;
      }
    }
    __syncthreads();

    // ---- phase B: 16 recurrence steps; wave-uniform variant on exact scheduled slot count
    asm volatile("" : "+s"(cnt));   // launder: block loop-unswitching (17x I$ blowup)
    if      (cnt <= 8)  { STEPLOOP(ENTS8)  }
    else if (cnt == 9)  { STEPLOOP(ENTS9)  }
    else if (cnt == 10) { STEPLOOP(ENTS10) }
    else if (cnt == 11) { STEPLOOP(ENTS11) }
    else if (cnt == 12) { STEPLOOP(ENTS12) }
    else if (cnt == 13) { STEPLOOP(ENTS13) }
    else if (cnt == 14) { STEPLOOP(ENTS14) }
    else if (cnt == 15) { STEPLOOP(ENTS15) }
    else if (cnt == 16) { STEPLOOP(ENTS16) }
    else if (cnt == 17) { STEPLOOP(ENTS17) }
    else if (cnt == 18) { STEPLOOP(ENTS18) }
    else if (cnt == 19) { STEPLOOP(ENTS19) }
    else if (cnt == 20) { STEPLOOP(ENTS20) }
    else if (cnt == 21) { STEPLOOP(ENTS21) }
    else if (cnt == 22) { STEPLOOP(ENTS22) }
    else if (cnt == 23) { STEPLOOP(ENTS23) }
    else                { STEPLOOP(ENTS24) }

    // ---- phase C: out_chunk from hbT (stride 1037 dwords -> conflict-free b128 reads)
    {
      f4_t oa0 = {0.f,0.f,0.f,0.f}, oa1 = {0.f,0.f,0.f,0.f};
      #pragma unroll
      for (int k4 = 0; k4 < 4; ++k4) {
        int kt = (wv << 2) + k4;
        union { uint4 q; bfvec v; } ha, w0, w1;
        ha.q = *(const uint4*)(smem + HBT_OFF + la15 * HBTROW + (kt << 6) + (lg << 4));
        w0.q = *(const uint4*)(woutf + (((size_t)(kt) * 64 + lane) << 2));
        w1.q = *(const uint4*)(woutf + (((size_t)(64 + kt) * 64 + lane) << 2));
        oa0 = __builtin_amdgcn_mfma_f32_16x16x32_bf16(ha.v, w0.v, oa0, 0, 0, 0);
        oa1 = __builtin_amdgcn_mfma_f32_16x16x32_bf16(ha.v, w1.v, oa1, 0, 0, 0);
      }
      float* os = oscratch + wv * OSWAVE;
      int tb = lg << 2;
      #pragma unroll
      for (int r = 0; r < 4; ++r) os[(tb + r) * OSW + la15] = oa0[r];
      #pragma unroll
      for (int r = 0; r < 4; ++r) os[(tb + r) * OSW + 16 + la15] = oa1[r];
    }
    __syncthreads();
    if (tid < 512) {
      float s = 0.0f;
      int ro = (tid >> 5) * OSW + (tid & 31);
      #pragma unroll
      for (int w2 = 0; w2 < 16; ++w2) s += oscratch[w2 * OSWAVE + ro];
      int tg = t0 + (tid >> 5);
      if (tg >= WASH - 1)
        out[((size_t)b * TO + (tg - (WASH - 1))) * NO + (tid & 31)] = s;
    }
    __syncthreads();  // protect u2/oscratch before next chunk's phase A
  }
}

extern "C" void kernel_launch(void* const* d_in, const int* in_sizes, int n_in,
                              void* d_out, int out_size, void* d_ws, size_t ws_size,
                              hipStream_t stream) {
  (void)in_sizes; (void)n_in; (void)out_size; (void)ws_size;
  const float* x    = (const float*)d_in[0];
  const float* Win  = (const float*)d_in[1];
  const float* A    = (const float*)d_in[2];
  const float* Wout = (const float*)d_in[3];
  float* out = (float*)d_out;

  char* ws = (char*)d_ws;
  uint32_t* ell      = (uint32_t*)(ws);              // 196608
  uint32_t* deg      = (uint32_t*)(ws + 196608);     // 8192
  uint32_t* perm     = (uint32_t*)(ws + 204800);     // 8192
  uint32_t* invp     = (uint32_t*)(ws + 212992);     // 8192
  uint32_t* pairrank = (uint32_t*)(ws + 221184);     // 4096
  uint32_t* pp       = (uint32_t*)(ws + 225280);     // 4096
  uint32_t* wavecnt  = (uint32_t*)(ws + 229376);     // 128
  uint32_t* pa       = (uint32_t*)(ws + 229504);     // 98304
  uint32_t* pva      = (uint32_t*)(ws + 327808);     // 98304
  uint32_t* pvb      = (uint32_t*)(ws + 426112);     // 98304
  uint32_t* winf     = (uint32_t*)(ws + 524416);     // 131072
  uint32_t* woutf    = (uint32_t*)(ws + 655488);     // 131072 (total 786560 B)

  hipFuncSetAttribute((const void*)rec_kernel,
                      hipFuncAttributeMaxDynamicSharedMemorySize, 160 * 1024);

  hipLaunchKernelGGL(build_ell, dim3(512), dim3(256), 0, stream, A, ell, deg);
  hipLaunchKernelGGL(sortperm, dim3(8), dim3(256), 0, stream, deg, perm, invp);
  hipLaunchKernelGGL(pairsort, dim3(4), dim3(256), 0, stream, deg, perm, pairrank, pp);
  hipLaunchKernelGGL(build_pairs, dim3(16), dim3(64), 0, stream,
                     ell, deg, perm, invp, pairrank, pp, pa, pva, pvb, wavecnt);
  hipLaunchKernelGGL(build_frags, dim3(256), dim3(256), 0, stream, Win, Wout, perm, pp, winf, woutf);
  hipLaunchKernelGGL(rec_kernel, dim3(16), dim3(1024), LDS_BYTES, stream,
                     x, pa, pva, pvb, wavecnt, winf, woutf, out);
}

// Round 13
// 2844.684 us; speedup vs baseline: 1.0303x; 1.0248x over previous
//
#include <hip/hip_runtime.h>
#include <stdint.h>

// Problem constants (fixed seed, fixed shapes)
#define BB 16
#define TT 2048
#define NI 32
#define NN 2048
#define NO 32
#define WASH 64
#define TO (TT - WASH + 1)   // 1985
#define W 24                 // per-row ELL cap
#define WT 24                // per-thread combined (pair) slot cap — COMPILE-TIME
#define CH 16                // time-chunk for fused MFMA GEMMs
// LDS layout (bytes):
//   hbT [16][4160] @ 0     : per-step h history ring; gathers read row (tt-1)&15, phase C reads all.
//                            stride 1040 dwords (16B-aligned; ≡16 mod 32 -> uniform bank rotation/step,
//                            schedule conflict-structure invariant)
//   u2  [16][4132] @ 66560 : input projection (stride 1033 dwords); oscratch overlays in phase C
#define HBTROW 4160
#define U2OFF 66560
#define UROWB 4132
#define OSW 35               // oscratch row stride (dwords), ≡3 mod 32
#define OSWAVE 560
#define LDS_BYTES (U2OFF + CH*UROWB)   // 66560 + 66112 = 132672

typedef short bfvec __attribute__((ext_vector_type(8)));   // 8 bf16 in 4 VGPRs
typedef float f4_t  __attribute__((ext_vector_type(4)));

__device__ inline unsigned short f2bf(float f) {
  unsigned int u = __builtin_bit_cast(unsigned int, f);
  unsigned int r = u + 0x7fffu + ((u >> 16) & 1u);   // RNE
  return (unsigned short)(r >> 16);
}
__device__ inline float bf2f(unsigned short s) {
  unsigned int u = ((unsigned int)s) << 16;
  return __builtin_bit_cast(float, u);
}
// clamp-free tanh: 1 - 2/(e^{2x}+1); exact at +-inf (exp2 saturates, rcp(inf)=0)
__device__ inline float tanh_fast(float x) {
  float e = __builtin_amdgcn_exp2f(x * 2.885390082f);   // 2^(2x*log2e) = e^{2x}
  float r = __builtin_amdgcn_rcpf(e + 1.0f);
  return __builtin_fmaf(-2.0f, r, 1.0f);
}

// ---------------- K1: dense A -> packed ELL (bf16 val << 16 | byte-offset col, NATURAL cols) ----
__global__ void build_ell(const float* __restrict__ A, uint32_t* __restrict__ ell,
                          uint32_t* __restrict__ deg) {
  int gw = (int)((blockIdx.x * blockDim.x + threadIdx.x) >> 6);  // one wave per row
  int lane = (int)(threadIdx.x & 63);
  if (gw >= NN) return;
  const float* row = A + (size_t)gw * NN;
  int base = 0;
  for (int c = 0; c < NN; c += 64) {
    float v = row[c + lane];
    bool nz = (v != 0.0f);
    unsigned long long mask = __ballot(nz);
    int pre = __popcll(mask & ((1ull << lane) - 1ull));
    if (nz) {
      int idx = base + pre;
      if (idx < W) {
        uint32_t packed = (((uint32_t)f2bf(v)) << 16) | (uint32_t)((c + lane) * 4);
        ell[(size_t)gw * W + idx] = packed;
      }
    }
    base += __popcll(mask);
  }
  int d = base < W ? base : W;
  if (lane == 0) deg[gw] = (uint32_t)d;
  for (int k = d + lane; k < W; k += 64) ell[(size_t)gw * W + k] = 0u;
}

// ---------------- K2: DETERMINISTIC rank sort by degree -> perm, invp (8 blocks parallel) ------
__global__ void sortperm(const uint32_t* __restrict__ deg, uint32_t* __restrict__ perm,
                         uint32_t* __restrict__ invp) {
  __shared__ int dg[NN];
  int tid = (int)threadIdx.x;                      // 256
  for (int i = tid; i < NN; i += 256) dg[i] = (int)deg[i];
  __syncthreads();
  int r = (int)blockIdx.x * 256 + tid;             // 8 blocks x 256 = 2048 rows
  int d = dg[r];
  int rank = 0;
  for (int j = 0; j < NN; ++j) {
    int dj = dg[j];
    rank += (dj < d) || (dj == d && j < r);
  }
  perm[rank] = (uint32_t)r;
  invp[r] = (uint32_t)rank;
}

// ---------------- K2c: rank sort of head-tail pairs by combined degree (4 blocks parallel) -----
__global__ void pairsort(const uint32_t* __restrict__ deg, const uint32_t* __restrict__ perm,
                         uint32_t* __restrict__ pairrank, uint32_t* __restrict__ pp) {
  __shared__ int ps[1024];
  int tid = (int)threadIdx.x;                      // 256
  for (int i = tid; i < 1024; i += 256) {
    int d0 = (int)deg[perm[i]]; if (d0 > W) d0 = W;
    int d1 = (int)deg[perm[2047 - i]]; if (d1 > W) d1 = W;
    int s = d0 + d1; if (s > WT) s = WT;
    ps[i] = s;
  }
  __syncthreads();
  int p = (int)blockIdx.x * 256 + tid;             // 4 blocks x 256 = 1024 pairs
  int s = ps[p];
  int rank = 0;
  for (int j = 0; j < 1024; ++j) {
    int sj = ps[j];
    rank += (sj < s) || (sj == s && j < p);
  }
  pairrank[p] = (uint32_t)rank;
  pp[rank] = (uint32_t)p;
}

// rank r -> store position (given pairrank)
__device__ inline int rank2pos(int r, const uint32_t* pairrank) {
  return (r < 1024) ? (2 * (int)pairrank[r]) : (2 * (int)pairrank[2047 - r] + 1);
}

// ---------------- K2b: entry tables + HALF-AWARE CONFLICT SCHEDULER ----------------------------
// Gather bank (step-0 frame) = (pos>>1)&31 = owner-thread&31; per-step the hbT ring rotates all
// banks uniformly (+16 per row index), which preserves the conflict structure exactly.
// Capacity 1 per (bank, 32-lane-half). 3 polite rounds + final (urgent lanes force).
// Deterministic (rotated-priority ballots). wavecnt[blk] = exact slot count S in [8,24].
__global__ void build_pairs(const uint32_t* __restrict__ ell, const uint32_t* __restrict__ deg,
                            const uint32_t* __restrict__ perm, const uint32_t* __restrict__ invp,
                            const uint32_t* __restrict__ pairrank, const uint32_t* __restrict__ pp,
                            uint32_t* __restrict__ pa, uint32_t* __restrict__ pva,
                            uint32_t* __restrict__ pvb, uint32_t* __restrict__ wavecnt) {
  int blk = (int)blockIdx.x;     // 0..15 (rec-wave)
  int lane = (int)threadIdx.x;   // 0..63
  int half = lane >> 5;
  int t = blk * 64 + lane;
  int p = (int)pp[t];
  uint32_t a_[WT], u_[WT], w_[WT];
  int cnt = 0;
  {
    int ro = (int)perm[p];                       // y0 row
    int d = (int)deg[ro]; if (d > W) d = W;
    for (int k = 0; k < d && cnt < WT; ++k) {
      uint32_t e = ell[(size_t)ro * W + k];
      int pos = rank2pos((int)invp[(e & 0xffffu) >> 2], pairrank);
      a_[cnt] = (uint32_t)(pos * 2);
      u_[cnt] = e & 0xffff0000u;
      w_[cnt] = 0u;
      ++cnt;
    }
    ro = (int)perm[2047 - p];                    // y1 row
    d = (int)deg[ro]; if (d > W) d = W;
    for (int k = 0; k < d && cnt < WT; ++k) {
      uint32_t e = ell[(size_t)ro * W + k];
      int pos = rank2pos((int)invp[(e & 0xffffu) >> 2], pairrank);
      a_[cnt] = (uint32_t)(pos * 2);
      u_[cnt] = 0u;
      w_[cnt] = e & 0xffff0000u;
      ++cnt;
    }
  }
  // wave max -> exact variant size S (8..24)
  int m = cnt;
  #pragma unroll
  for (int off = 32; off; off >>= 1) m = max(m, __shfl_xor(m, off));
  int S = m < 8 ? 8 : (m > 24 ? 24 : m);
  if (lane == 0) wavecnt[blk] = (uint32_t)S;

  uint32_t sa[WT], su[WT], sw[WT];
  for (int s = 0; s < WT; ++s) {                 // defaults (pads / slots >= S)
    sa[s] = ((uint32_t)((lane + s) & 31)) << 2;
    su[s] = 0u; sw[s] = 0u;
  }
  uint32_t used = 0;
  int rem = cnt;
  for (int s = 0; s < S; ++s) {
    unsigned long long occ = 0ull;               // bit (half*32 + bank)
    bool placed = false;
    const int R = 4;
    for (int r = 0; r < R; ++r) {
      bool last = (r == R - 1);
      bool urgent = (rem >= S - s);
      int pk = -1, pb = 32;
      if (!placed && rem > 0) {
        for (int k = 0; k < WT; ++k) {           // first remaining entry with free bank (my half)
          if (k >= cnt) break;
          if ((used >> k) & 1u) continue;
          int b = (int)((a_[k] >> 2) & 31u);
          if (!((occ >> (half * 32 + b)) & 1ull)) { pk = k; pb = b; break; }
        }
        if (pk < 0 && last && urgent) {          // urgent: any remaining entry
          for (int k = 0; k < WT; ++k) {
            if (k >= cnt) break;
            if (!((used >> k) & 1u)) {
              pk = k;
              pb = (int)((a_[k] >> 2) & 31u);
              break;
            }
          }
        }
      }
      int shift = (s * 19 + r * 7) & 31;
      for (int b = 0; b < 32; ++b) {
        unsigned long long mb = __ballot(pb == b);
        if (!mb) continue;
        for (int h = 0; h < 2; ++h) {
          uint32_t mh = (uint32_t)(mb >> (h * 32));
          if (!mh) continue;
          bool freeb = !((occ >> (h * 32 + b)) & 1ull);
          uint32_t mhr = (mh >> shift) | (mh << ((32 - shift) & 31));
          int winpos = __ffs(mhr) - 1;
          int winlane = ((winpos + shift) & 31) + h * 32;
          if (freeb) occ |= 1ull << (h * 32 + b);
          if (pb == b && half == h && !placed) {
            bool win = (lane == winlane);
            if ((freeb && win) || (last && urgent)) {
              placed = true;
              used |= 1u << (unsigned)pk;
              sa[s] = a_[pk];
              su[s] = u_[pk]; sw[s] = w_[pk];
              rem--;
            }
          }
        }
      }
    }
    if (!placed) {
      // pad: free bank in my half scanning from lane+s (reads valid h data, values are zero)
      int pick = (lane + s) & 31;
      for (int j = 0; j < 32; ++j) {
        int b = (lane + s + j) & 31;
        if (!((occ >> (half * 32 + b)) & 1ull)) { pick = b; break; }
      }
      sa[s] = ((uint32_t)pick) << 2;
    }
  }
  for (int k = 0; k < WT; ++k) {
    pa[(size_t)t * WT + k] = sa[k];
    pva[(size_t)t * WT + k] = su[k];
    pvb[(size_t)t * WT + k] = sw[k];
  }
}

// ---------------- K3: Win/Wout -> MFMA fragment order (bf16 pairs), store-order n --------------
__global__ void build_frags(const float* __restrict__ Win, const float* __restrict__ Wout,
                            const uint32_t* __restrict__ perm, const uint32_t* __restrict__ pp,
                            uint32_t* __restrict__ winf, uint32_t* __restrict__ woutf) {
  int f = (int)(blockIdx.x * blockDim.x + threadIdx.x);  // 0..65535
  if (f < 32768) {
    int reg = f & 3, lane = (f >> 2) & 63, ntg = f >> 8;
    int n = (ntg << 4) + (lane & 15);
    int k = ((lane >> 4) << 3) + reg * 2;
    int p = (int)pp[n >> 1];
    int np = (int)perm[(n & 1) ? (2047 - p) : p];
    uint32_t lo = f2bf(Win[(size_t)np * NI + k]);
    uint32_t hi = f2bf(Win[(size_t)np * NI + k + 1]);
    winf[f] = lo | (hi << 16);
  } else {
    int g = f - 32768;
    int reg = g & 3, lane = (g >> 2) & 63, kt = (g >> 8) & 63, ot = g >> 14;
    int o = (ot << 4) + (lane & 15);
    int n = (kt << 5) + ((lane >> 4) << 3) + reg * 2;   // even
    int p = (int)pp[n >> 1];
    int n0 = (int)perm[p];
    int n1 = (int)perm[2047 - p];
    uint32_t lo = f2bf(Wout[(size_t)o * NN + n0]);
    uint32_t hi = f2bf(Wout[(size_t)o * NN + n1]);
    woutf[g] = lo | (hi << 16);
  }
}

// ---------------- K4: fused recurrence (1 workgroup per batch) ---------------------------------
// Single h buffer: hbT ring. Step tt gathers from row (tt-1)&15, writes row tt. Phase C reads
// all 16 rows (stride 1040 dwords, 16B-aligned).
#define ENT(K)                                                                       \
  {                                                                                  \
    float hv = bf2f(*(const unsigned short*)(smem + po0 + ea##K));                   \
    y0 = __builtin_fmaf(__builtin_bit_cast(float, va##K), hv, y0);                   \
    y1 = __builtin_fmaf(__builtin_bit_cast(float, vb##K), hv, y1);                   \
  }

#define ENTS8  ENT(0) ENT(1) ENT(2) ENT(3) ENT(4) ENT(5) ENT(6) ENT(7)
#define ENTS9  ENTS8  ENT(8)
#define ENTS10 ENTS9  ENT(9)
#define ENTS11 ENTS10 ENT(10)
#define ENTS12 ENTS11 ENT(11)
#define ENTS13 ENTS12 ENT(12)
#define ENTS14 ENTS13 ENT(13)
#define ENTS15 ENTS14 ENT(14)
#define ENTS16 ENTS15 ENT(15)
#define ENTS17 ENTS16 ENT(16)
#define ENTS18 ENTS17 ENT(17)
#define ENTS19 ENTS18 ENT(18)
#define ENTS20 ENTS19 ENT(19)
#define ENTS21 ENTS20 ENT(20)
#define ENTS22 ENTS21 ENT(21)
#define ENTS23 ENTS22 ENT(22)
#define ENTS24 ENTS23 ENT(23)

// rolled 16-step loop (forced no-unroll: 17 variants must fit I$)
#define STEPLOOP(ENTS)                                                               \
  _Pragma("unroll 1")                                                                \
  for (int tt = 0; tt < CH; ++tt) {                                                  \
    const int po0 = ((tt + CH - 1) & (CH - 1)) * HBTROW;                             \
    uint32_t uw = *(const uint32_t*)(smem + u2a + tt * UROWB);                       \
    float y0 = bf2f((unsigned short)(uw & 0xffffu));                                 \
    float y1 = bf2f((unsigned short)(uw >> 16));                                     \
    ENTS                                                                             \
    float hn0 = __builtin_fmaf(0.9f, tanh_fast(y0), 0.1f * h0);                      \
    float hn1 = __builtin_fmaf(0.9f, tanh_fast(y1), 0.1f * h1);                      \
    uint32_t wpk;                                                                    \
    asm("v_cvt_pk_bf16_f32 %0, %1, %2" : "=v"(wpk) : "v"(hn0), "v"(hn1));            \
    *(uint32_t*)(smem + hwa + tt * HBTROW) = wpk;                                    \
    h0 = hn0; h1 = hn1;                                                              \
    __syncthreads();                                                                 \
  }

__global__ __launch_bounds__(1024, 1) void rec_kernel(
    const float* __restrict__ x,
    const uint32_t* __restrict__ pa, const uint32_t* __restrict__ pva,
    const uint32_t* __restrict__ pvb, const uint32_t* __restrict__ wavecnt,
    const uint32_t* __restrict__ winf, const uint32_t* __restrict__ woutf,
    float* __restrict__ out) {
  extern __shared__ char smem[];
  float* oscratch = (float*)(smem + U2OFF);       // overlays u2 during phase C

  const int tid = (int)threadIdx.x;
  const int b = (int)blockIdx.x;
  const int lane = tid & 63;
  const int wv = tid >> 6;
  const int la15 = lane & 15;
  const int lg = lane >> 4;
  const int u2a = U2OFF + (tid << 2);
  const int hwa = tid << 2;

  int cnt = __builtin_amdgcn_readfirstlane((int)wavecnt[wv]);

  // entry tables -> 72 NAMED scalars (no arrays, no alloca, no scratch)
  uint32_t ea0, ea1, ea2, ea3, ea4, ea5, ea6, ea7, ea8, ea9, ea10, ea11,
           ea12, ea13, ea14, ea15, ea16, ea17, ea18, ea19, ea20, ea21, ea22, ea23;
  uint32_t va0, va1, va2, va3, va4, va5, va6, va7, va8, va9, va10, va11,
           va12, va13, va14, va15, va16, va17, va18, va19, va20, va21, va22, va23;
  uint32_t vb0, vb1, vb2, vb3, vb4, vb5, vb6, vb7, vb8, vb9, vb10, vb11,
           vb12, vb13, vb14, vb15, vb16, vb17, vb18, vb19, vb20, vb21, vb22, vb23;
  {
    const uint4* qa = (const uint4*)(pa + (size_t)tid * WT);
    const uint4* qv = (const uint4*)(pva + (size_t)tid * WT);
    const uint4* qw = (const uint4*)(pvb + (size_t)tid * WT);
    uint4 A0 = qa[0], A1 = qa[1], A2 = qa[2], A3 = qa[3], A4 = qa[4], A5 = qa[5];
    uint4 V0 = qv[0], V1 = qv[1], V2 = qv[2], V3 = qv[3], V4 = qv[4], V5 = qv[5];
    uint4 B0 = qw[0], B1 = qw[1], B2 = qw[2], B3 = qw[3], B4 = qw[4], B5 = qw[5];
    ea0 = A0.x; ea1 = A0.y; ea2 = A0.z; ea3 = A0.w;
    ea4 = A1.x; ea5 = A1.y; ea6 = A1.z; ea7 = A1.w;
    ea8 = A2.x; ea9 = A2.y; ea10 = A2.z; ea11 = A2.w;
    ea12 = A3.x; ea13 = A3.y; ea14 = A3.z; ea15 = A3.w;
    ea16 = A4.x; ea17 = A4.y; ea18 = A4.z; ea19 = A4.w;
    ea20 = A5.x; ea21 = A5.y; ea22 = A5.z; ea23 = A5.w;
    va0 = V0.x; va1 = V0.y; va2 = V0.z; va3 = V0.w;
    va4 = V1.x; va5 = V1.y; va6 = V1.z; va7 = V1.w;
    va8 = V2.x; va9 = V2.y; va10 = V2.z; va11 = V2.w;
    va12 = V3.x; va13 = V3.y; va14 = V3.z; va15 = V3.w;
    va16 = V4.x; va17 = V4.y; va18 = V4.z; va19 = V4.w;
    va20 = V5.x; va21 = V5.y; va22 = V5.z; va23 = V5.w;
    vb0 = B0.x; vb1 = B0.y; vb2 = B0.z; vb3 = B0.w;
    vb4 = B1.x; vb5 = B1.y; vb6 = B1.z; vb7 = B1.w;
    vb8 = B2.x; vb9 = B2.y; vb10 = B2.z; vb11 = B2.w;
    vb12 = B3.x; vb13 = B3.y; vb14 = B3.z; vb15 = B3.w;
    vb16 = B4.x; vb17 = B4.y; vb18 = B4.z; vb19 = B4.w;
    vb20 = B5.x; vb21 = B5.y; vb22 = B5.z; vb23 = B5.w;
  }

  // h(t=-1) = 0: zero hbT row 15 (step 0 reads row 15)
  *(uint32_t*)(smem + 15 * HBTROW + (tid << 2)) = 0u;
  float h0 = 0.0f, h1 = 0.0f;

  for (int c = 0; c < TT / CH; ++c) {
    const int t0 = c * CH;

    // ---- phase A: u2 = Win_store . x_chunk^T via MFMA (D row=n, col=t); wave wv: n in [wv*128,+128)
    {
      const float* xp = x + ((size_t)b * TT + (t0 + la15)) * NI + (lg << 3);
      float4 x0 = *(const float4*)xp;
      float4 x1 = *(const float4*)(xp + 4);
      union { unsigned short u16[8]; bfvec v; } af;   // B-operand: col=t=la15, k=i
      af.u16[0]=f2bf(x0.x); af.u16[1]=f2bf(x0.y); af.u16[2]=f2bf(x0.z); af.u16[3]=f2bf(x0.w);
      af.u16[4]=f2bf(x1.x); af.u16[5]=f2bf(x1.y); af.u16[6]=f2bf(x1.z); af.u16[7]=f2bf(x1.w);
      #pragma unroll
      for (int nt = 0; nt < 8; ++nt) {
        int ntg = (wv << 3) + nt;
        union { uint4 q; bfvec v; } bw;               // A-operand: row=n=la15-in-tile, k=i
        bw.q = *(const uint4*)(winf + (((size_t)ntg * 64 + lane) << 2));
        f4_t acc = {0.f, 0.f, 0.f, 0.f};
        acc = __builtin_amdgcn_mfma_f32_16x16x32_bf16(bw.v, af.v, acc, 0, 0, 0);
        int dw = (ntg << 3) + (lg << 1);              // dword index = n>>1
        uint32_t w0 = (uint32_t)f2bf(acc[0]) | ((uint32_t)f2bf(acc[1]) << 16);
        uint32_t w1 = (uint32_t)f2bf(acc[2]) | ((uint32_t)f2bf(acc[3]) << 16);
        char* ub = smem + U2OFF + la15 * UROWB + (dw << 2);
        *(uint32_t*)(ub) = w0;
        *(uint32_t*)(ub + 4) = w1;
      }
    }
    __syncthreads();

    // ---- phase B: 16 recurrence steps; wave-uniform variant on exact scheduled slot count
    asm volatile("" : "+s"(cnt));   // launder: block loop-unswitching (17x I$ blowup)
    if      (cnt <= 8)  { STEPLOOP(ENTS8)  }
    else if (cnt == 9)  { STEPLOOP(ENTS9)  }
    else if (cnt == 10) { STEPLOOP(ENTS10) }
    else if (cnt == 11) { STEPLOOP(ENTS11) }
    else if (cnt == 12) { STEPLOOP(ENTS12) }
    else if (cnt == 13) { STEPLOOP(ENTS13) }
    else if (cnt == 14) { STEPLOOP(ENTS14) }
    else if (cnt == 15) { STEPLOOP(ENTS15) }
    else if (cnt == 16) { STEPLOOP(ENTS16) }
    else if (cnt == 17) { STEPLOOP(ENTS17) }
    else if (cnt == 18) { STEPLOOP(ENTS18) }
    else if (cnt == 19) { STEPLOOP(ENTS19) }
    else if (cnt == 20) { STEPLOOP(ENTS20) }
    else if (cnt == 21) { STEPLOOP(ENTS21) }
    else if (cnt == 22) { STEPLOOP(ENTS22) }
    else if (cnt == 23) { STEPLOOP(ENTS23) }
    else                { STEPLOOP(ENTS24) }

    // ---- phase C: out_chunk from hbT (stride 1040 dwords, 16B-aligned b128 reads)
    {
      f4_t oa0 = {0.f,0.f,0.f,0.f}, oa1 = {0.f,0.f,0.f,0.f};
      #pragma unroll
      for (int k4 = 0; k4 < 4; ++k4) {
        int kt = (wv << 2) + k4;
        union { uint4 q; bfvec v; } ha, w0, w1;
        ha.q = *(const uint4*)(smem + la15 * HBTROW + (kt << 6) + (lg << 4));
        w0.q = *(const uint4*)(woutf + (((size_t)(kt) * 64 + lane) << 2));
        w1.q = *(const uint4*)(woutf + (((size_t)(64 + kt) * 64 + lane) << 2));
        oa0 = __builtin_amdgcn_mfma_f32_16x16x32_bf16(ha.v, w0.v, oa0, 0, 0, 0);
        oa1 = __builtin_amdgcn_mfma_f32_16x16x32_bf16(ha.v, w1.v, oa1, 0, 0, 0);
      }
      float* os = oscratch + wv * OSWAVE;
      int tb = lg << 2;
      #pragma unroll
      for (int r = 0; r < 4; ++r) os[(tb + r) * OSW + la15] = oa0[r];
      #pragma unroll
      for (int r = 0; r < 4; ++r) os[(tb + r) * OSW + 16 + la15] = oa1[r];
    }
    __syncthreads();
    if (tid < 512) {
      float s = 0.0f;
      int ro = (tid >> 5) * OSW + (tid & 31);
      #pragma unroll
      for (int w2 = 0; w2 < 16; ++w2) s += oscratch[w2 * OSWAVE + ro];
      int tg = t0 + (tid >> 5);
      if (tg >= WASH - 1)
        out[((size_t)b * TO + (tg - (WASH - 1))) * NO + (tid & 31)] = s;
    }
    __syncthreads();  // protect u2/oscratch before next chunk's phase A
  }
}

extern "C" void kernel_launch(void* const* d_in, const int* in_sizes, int n_in,
                              void* d_out, int out_size, void* d_ws, size_t ws_size,
                              hipStream_t stream) {
  (void)in_sizes; (void)n_in; (void)out_size; (void)ws_size;
  const float* x    = (const float*)d_in[0];
  const float* Win  = (const float*)d_in[1];
  const float* A    = (const float*)d_in[2];
  const float* Wout = (const float*)d_in[3];
  float* out = (float*)d_out;

  char* ws = (char*)d_ws;
  uint32_t* ell      = (uint32_t*)(ws);              // 196608
  uint32_t* deg      = (uint32_t*)(ws + 196608);     // 8192
  uint32_t* perm     = (uint32_t*)(ws + 204800);     // 8192
  uint32_t* invp     = (uint32_t*)(ws + 212992);     // 8192
  uint32_t* pairrank = (uint32_t*)(ws + 221184);     // 4096
  uint32_t* pp       = (uint32_t*)(ws + 225280);     // 4096
  uint32_t* wavecnt  = (uint32_t*)(ws + 229376);     // 128
  uint32_t* pa       = (uint32_t*)(ws + 229504);     // 98304
  uint32_t* pva      = (uint32_t*)(ws + 327808);     // 98304
  uint32_t* pvb      = (uint32_t*)(ws + 426112);     // 98304
  uint32_t* winf     = (uint32_t*)(ws + 524416);     // 131072
  uint32_t* woutf    = (uint32_t*)(ws + 655488);     // 131072 (total 786560 B)

  hipFuncSetAttribute((const void*)rec_kernel,
                      hipFuncAttributeMaxDynamicSharedMemorySize, 160 * 1024);

  hipLaunchKernelGGL(build_ell, dim3(512), dim3(256), 0, stream, A, ell, deg);
  hipLaunchKernelGGL(sortperm, dim3(8), dim3(256), 0, stream, deg, perm, invp);
  hipLaunchKernelGGL(pairsort, dim3(4), dim3(256), 0, stream, deg, perm, pairrank, pp);
  hipLaunchKernelGGL(build_pairs, dim3(16), dim3(64), 0, stream,
                     ell, deg, perm, invp, pairrank, pp, pa, pva, pvb, wavecnt);
  hipLaunchKernelGGL(build_frags, dim3(256), dim3(256), 0, stream, Win, Wout, perm, pp, winf, woutf);
  hipLaunchKernelGGL(rec_kernel, dim3(16), dim3(1024), LDS_BYTES, stream,
                     x, pa, pva, pvb, wavecnt, winf, woutf, out);
}